// Round 1
// baseline (359.469 us; speedup 1.0000x reference)
//
#include <hip/hip_runtime.h>

typedef short s8v __attribute__((ext_vector_type(8)));
typedef float f32x4 __attribute__((ext_vector_type(4)));

#define DEVI static __device__ __forceinline__

namespace {
constexpr int B_  = 2;
constexpr int N_  = 4096;
constexpr int KS_ = 8;
constexpr int C_  = 192;
constexpr int H_  = 8;
constexpr int D_  = 24;
constexpr int NT_ = 4104;        // N_ + KS_
constexpr int TC_ = 576;         // 3*C_
constexpr int NP_ = 4160;        // kv rows padded to 65*64
constexpr int DP_ = 32;          // head dim padded for K=32 MFMA
constexpr int M_  = B_ * NT_;    // 8208 total rows
}

DEVI unsigned short f2bf(float f) {
  union { float f; unsigned u; } x; x.f = f;
  unsigned r = x.u + 0x7FFFu + ((x.u >> 16) & 1u);   // RNE
  return (unsigned short)(r >> 16);
}

DEVI f32x4 mfma16(s8v a, s8v b, f32x4 c) {
  return __builtin_amdgcn_mfma_f32_16x16x32_bf16(a, b, c, 0, 0, 0);
}

DEVI void store_bf4(unsigned short* dst, float4 v) {
  uint2 p;
  p.x = (unsigned)f2bf(v.x) | ((unsigned)f2bf(v.y) << 16);
  p.y = (unsigned)f2bf(v.z) | ((unsigned)f2bf(v.w) << 16);
  *reinterpret_cast<uint2*>(dst) = p;
}

// ---------------- kernel 1: QKV projection (bf16 MFMA GEMM + scatter) -------
__global__ __launch_bounds__(256) void qkv_kernel(
    const float* __restrict__ X, const float* __restrict__ S,
    const float* __restrict__ Wqkv,
    unsigned short* __restrict__ Qb, unsigned short* __restrict__ Kb,
    unsigned short* __restrict__ Vt)
{
  __shared__ __align__(16) unsigned short Al[64 * 200];  // 64 rows x 192, stride 200
  __shared__ __align__(16) unsigned short Wl[64 * 200];
  const int tid = threadIdx.x;
  const int m0 = blockIdx.x * 64, o0 = blockIdx.y * 64;
  {
    const int r = tid >> 2, c0 = (tid & 3) * 48;
    const int g = m0 + r;
    if (g < M_) {
      const int b = g / NT_, n = g % NT_;
      const float* src = (n < N_) ? (X + ((size_t)b * N_ + n) * C_)
                                  : (S + ((size_t)b * KS_ + (n - N_)) * C_);
      #pragma unroll
      for (int j = 0; j < 48; j += 4)
        store_bf4(&Al[r * 200 + c0 + j], *reinterpret_cast<const float4*>(src + c0 + j));
    }
    const float* wsrc = Wqkv + (size_t)(o0 + r) * C_;
    #pragma unroll
    for (int j = 0; j < 48; j += 4)
      store_bf4(&Wl[r * 200 + c0 + j], *reinterpret_cast<const float4*>(wsrc + c0 + j));
  }
  __syncthreads();
  const int w = tid >> 6, lane = tid & 63, lr = lane & 15, lg = lane >> 4;
  f32x4 acc[4] = {};
  #pragma unroll
  for (int kk = 0; kk < 6; ++kk) {
    s8v af = *reinterpret_cast<const s8v*>(&Al[(w * 16 + lr) * 200 + kk * 32 + lg * 8]);
    #pragma unroll
    for (int f = 0; f < 4; ++f) {
      s8v bf = *reinterpret_cast<const s8v*>(&Wl[(f * 16 + lr) * 200 + kk * 32 + lg * 8]);
      acc[f] = mfma16(af, bf, acc[f]);
    }
  }
  #pragma unroll
  for (int f = 0; f < 4; ++f) {
    #pragma unroll
    for (int r4 = 0; r4 < 4; ++r4) {
      const int grow = m0 + w * 16 + lg * 4 + r4;
      if (grow >= M_) continue;
      const int b = grow / NT_, n = grow % NT_;
      const int o = o0 + f * 16 + lr;
      const unsigned short bv = f2bf(acc[f][r4]);
      const int which = o / C_, oc = o % C_;
      const int h = oc / D_, d = oc % D_;
      const int bh = b * H_ + h;
      if (which == 0)      Qb[((size_t)bh * NP_ + n) * DP_ + d] = bv;
      else if (which == 1) Kb[((size_t)bh * NP_ + n) * DP_ + d] = bv;
      else                 Vt[((size_t)bh * DP_ + d) * NP_ + n] = bv;   // V transposed
    }
  }
}

// ---------------- kernel 2: flash attention -------------------------------
__global__ __launch_bounds__(256) void attn_kernel(
    const unsigned short* __restrict__ Qb, const unsigned short* __restrict__ Kb,
    const unsigned short* __restrict__ Vt, const float* __restrict__ temp,
    unsigned short* __restrict__ AO)
{
  __shared__ __align__(16) unsigned short Kl[64 * 40];      // K tile [64 kv][32 d], stride 40
  __shared__ __align__(16) unsigned short Vl[32 * 72];      // V^T tile [32 d][64 kv], stride 72
  __shared__ __align__(16) unsigned short Pl[4 * 32 * 72];  // per-wave P [32 q][64 kv]
  const int bh = blockIdx.y, h = bh & (H_ - 1), b = bh >> 3;
  const int q0 = blockIdx.x * 128;
  const int tid = threadIdx.x, w = tid >> 6, lane = tid & 63, lr = lane & 15, lg = lane >> 4;
  const float ts = temp[h];
  const unsigned short* Qp = Qb + (size_t)bh * NP_ * DP_;
  const unsigned short* Kp = Kb + (size_t)bh * NP_ * DP_;
  const unsigned short* Vp = Vt + (size_t)bh * DP_ * NP_;

  // Q fragments live in registers for the whole kernel (row = lane&15, k = d)
  s8v qf[2];
  #pragma unroll
  for (int mi = 0; mi < 2; ++mi) {
    int r = q0 + w * 32 + mi * 16 + lr;
    if (r > NT_ - 1) r = NT_ - 1;                 // clamp (rows >= NT_ never stored)
    qf[mi] = *reinterpret_cast<const s8v*>(&Qp[(size_t)r * DP_ + lg * 8]);
  }
  f32x4 oacc[2][2] = {};
  float mrow[2][4], lsum[2][4];
  #pragma unroll
  for (int mi = 0; mi < 2; ++mi)
    #pragma unroll
    for (int r4 = 0; r4 < 4; ++r4) { mrow[mi][r4] = -1e30f; lsum[mi][r4] = 0.f; }
  unsigned short* Pw = &Pl[w * 32 * 72];

  for (int t = 0; t < NP_ / 64; ++t) {
    {
      const int r = tid >> 2, c0 = (tid & 3) * 8;
      *reinterpret_cast<s8v*>(&Kl[r * 40 + c0]) =
          *reinterpret_cast<const s8v*>(&Kp[((size_t)t * 64 + r) * DP_ + c0]);
      const int dr = tid >> 3, cv = (tid & 7) * 8;
      *reinterpret_cast<s8v*>(&Vl[dr * 72 + cv]) =
          *reinterpret_cast<const s8v*>(&Vp[(size_t)dr * NP_ + t * 64 + cv]);
    }
    __syncthreads();

    s8v kf[4];
    #pragma unroll
    for (int nf = 0; nf < 4; ++nf)
      kf[nf] = *reinterpret_cast<const s8v*>(&Kl[(nf * 16 + lr) * 40 + lg * 8]);

    f32x4 sa[2][4];
    #pragma unroll
    for (int mi = 0; mi < 2; ++mi)
      #pragma unroll
      for (int nf = 0; nf < 4; ++nf) {
        f32x4 z = {};
        sa[mi][nf] = mfma16(qf[mi], kf[nf], z);
      }

    const int kvbase = t * 64;
    #pragma unroll
    for (int mi = 0; mi < 2; ++mi) {
      // temperature scale + tail mask
      #pragma unroll
      for (int nf = 0; nf < 4; ++nf) {
        const bool valid = (kvbase + nf * 16 + lr) < NT_;
        #pragma unroll
        for (int r4 = 0; r4 < 4; ++r4)
          sa[mi][nf][r4] = valid ? sa[mi][nf][r4] * ts : -1e30f;
      }
      // online softmax; S rows (q) are lane-local: row = lg*4 + r4
      float pm[4];
      #pragma unroll
      for (int r4 = 0; r4 < 4; ++r4)
        pm[r4] = fmaxf(fmaxf(sa[mi][0][r4], sa[mi][1][r4]),
                       fmaxf(sa[mi][2][r4], sa[mi][3][r4]));
      #pragma unroll
      for (int off = 1; off < 16; off <<= 1)
        #pragma unroll
        for (int r4 = 0; r4 < 4; ++r4)
          pm[r4] = fmaxf(pm[r4], __shfl_xor(pm[r4], off));
      #pragma unroll
      for (int r4 = 0; r4 < 4; ++r4) {
        const float mn = fmaxf(mrow[mi][r4], pm[r4]);
        const float corr = __expf(mrow[mi][r4] - mn);
        mrow[mi][r4] = mn;
        float rs = 0.f;
        #pragma unroll
        for (int nf = 0; nf < 4; ++nf) {
          const float p = __expf(sa[mi][nf][r4] - mn);
          sa[mi][nf][r4] = p;
          rs += p;
        }
        #pragma unroll
        for (int off = 1; off < 16; off <<= 1)
          rs += __shfl_xor(rs, off);
        lsum[mi][r4] = lsum[mi][r4] * corr + rs;
        #pragma unroll
        for (int df = 0; df < 2; ++df)
          oacc[mi][df][r4] *= corr;
        #pragma unroll
        for (int nf = 0; nf < 4; ++nf)
          Pw[(mi * 16 + lg * 4 + r4) * 72 + nf * 16 + lr] = f2bf(sa[mi][nf][r4]);
      }
    }
    // make P visible (wave-local LDS round-trip)
    asm volatile("s_waitcnt lgkmcnt(0)" ::: "memory");

    #pragma unroll
    for (int mi = 0; mi < 2; ++mi)
      #pragma unroll
      for (int ks = 0; ks < 2; ++ks) {
        s8v pa = *reinterpret_cast<const s8v*>(&Pw[(mi * 16 + lr) * 72 + ks * 32 + lg * 8]);
        #pragma unroll
        for (int df = 0; df < 2; ++df) {
          s8v vb = *reinterpret_cast<const s8v*>(&Vl[(df * 16 + lr) * 72 + ks * 32 + lg * 8]);
          oacc[mi][df] = mfma16(pa, vb, oacc[mi][df]);
        }
      }
    __syncthreads();
  }

  #pragma unroll
  for (int mi = 0; mi < 2; ++mi)
    #pragma unroll
    for (int r4 = 0; r4 < 4; ++r4) {
      const int row = q0 + w * 32 + mi * 16 + lg * 4 + r4;
      if (row >= NT_) continue;
      const float inv = 1.f / lsum[mi][r4];
      #pragma unroll
      for (int df = 0; df < 2; ++df) {
        const int d = df * 16 + lr;
        if (d < D_)
          AO[((size_t)b * NT_ + row) * C_ + h * D_ + d] = f2bf(oacc[mi][df][r4] * inv);
      }
    }
}

// ---------------- kernel 3: output projection ------------------------------
__global__ __launch_bounds__(256) void outproj_kernel(
    const unsigned short* __restrict__ AO, const float* __restrict__ Wout,
    float* __restrict__ out)
{
  __shared__ __align__(16) unsigned short Al[64 * 200];
  __shared__ __align__(16) unsigned short Wl[64 * 200];
  const int tid = threadIdx.x;
  const int m0 = blockIdx.x * 64, o0 = blockIdx.y * 64;
  {
    const int r = tid >> 2, c0 = (tid & 3) * 48;
    int g = m0 + r; if (g > M_ - 1) g = M_ - 1;
    #pragma unroll
    for (int j = 0; j < 48; j += 8)
      *reinterpret_cast<s8v*>(&Al[r * 200 + c0 + j]) =
          *reinterpret_cast<const s8v*>(&AO[(size_t)g * C_ + c0 + j]);
    const float* wsrc = Wout + (size_t)(o0 + r) * C_;
    #pragma unroll
    for (int j = 0; j < 48; j += 4)
      store_bf4(&Wl[r * 200 + c0 + j], *reinterpret_cast<const float4*>(wsrc + c0 + j));
  }
  __syncthreads();
  const int w = tid >> 6, lane = tid & 63, lr = lane & 15, lg = lane >> 4;
  f32x4 acc[4] = {};
  #pragma unroll
  for (int kk = 0; kk < 6; ++kk) {
    s8v af = *reinterpret_cast<const s8v*>(&Al[(w * 16 + lr) * 200 + kk * 32 + lg * 8]);
    #pragma unroll
    for (int f = 0; f < 4; ++f) {
      s8v bf = *reinterpret_cast<const s8v*>(&Wl[(f * 16 + lr) * 200 + kk * 32 + lg * 8]);
      acc[f] = mfma16(af, bf, acc[f]);
    }
  }
  #pragma unroll
  for (int f = 0; f < 4; ++f)
    #pragma unroll
    for (int r4 = 0; r4 < 4; ++r4) {
      const int grow = m0 + w * 16 + lg * 4 + r4;
      if (grow >= M_) continue;
      const int b = grow / NT_, n = grow % NT_;
      if (n >= N_) continue;                       // drop strategy-token rows
      out[((size_t)b * N_ + n) * C_ + o0 + f * 16 + lr] = acc[f][r4];
    }
}

// ---------------- launch ---------------------------------------------------
extern "C" void kernel_launch(void* const* d_in, const int* in_sizes, int n_in,
                              void* d_out, int out_size, void* d_ws, size_t ws_size,
                              hipStream_t stream) {
  const float* X    = (const float*)d_in[0];
  const float* S    = (const float*)d_in[1];
  const float* Wqkv = (const float*)d_in[2];
  const float* Wout = (const float*)d_in[3];
  const float* temp = (const float*)d_in[4];
  float* out = (float*)d_out;

  unsigned short* Qb = (unsigned short*)d_ws;
  const size_t qkv_elems = (size_t)B_ * H_ * NP_ * DP_;   // 2,129,920 shorts each
  unsigned short* Kb = Qb + qkv_elems;
  unsigned short* Vt = Kb + qkv_elems;
  unsigned short* AO = Vt + qkv_elems;                    // [M_][C_] bf16
  // total ws: (3*2,129,920 + 8208*192)*2 B ~= 15.9 MB

  qkv_kernel<<<dim3((M_ + 63) / 64, TC_ / 64), 256, 0, stream>>>(X, S, Wqkv, Qb, Kb, Vt);
  attn_kernel<<<dim3((NT_ + 127) / 128, B_ * H_), 256, 0, stream>>>(Qb, Kb, Vt, temp, AO);
  outproj_kernel<<<dim3((M_ + 63) / 64, C_ / 64), 256, 0, stream>>>(AO, Wout, out);
}

// Round 2
// 224.188 us; speedup vs baseline: 1.6034x; 1.6034x over previous
//
#include <hip/hip_runtime.h>

typedef short s8v __attribute__((ext_vector_type(8)));
typedef float f32x4 __attribute__((ext_vector_type(4)));

#define DEVI static __device__ __forceinline__

namespace {
constexpr int B_  = 2;
constexpr int N_  = 4096;
constexpr int KS_ = 8;
constexpr int C_  = 192;
constexpr int H_  = 8;
constexpr int D_  = 24;
constexpr int NT_ = 4104;        // N_ + KS_
constexpr int TC_ = 576;         // 3*C_
constexpr int NP_ = 4160;        // kv rows padded to 65*64
constexpr int DP_ = 32;          // head dim padded for K=32 MFMA
constexpr int M_  = B_ * NT_;    // 8208 total rows
constexpr float LOG2E_ = 1.4426950408889634f;
}

DEVI unsigned short f2bf(float f) {
  union { float f; unsigned u; } x; x.f = f;
  unsigned r = x.u + 0x7FFFu + ((x.u >> 16) & 1u);   // RNE
  return (unsigned short)(r >> 16);
}

DEVI f32x4 mfma16(s8v a, s8v b, f32x4 c) {
  return __builtin_amdgcn_mfma_f32_16x16x32_bf16(a, b, c, 0, 0, 0);
}

DEVI unsigned cvt_pk_bf16(float lo, float hi) {
  unsigned r;
  asm("v_cvt_pk_bf16_f32 %0, %1, %2" : "=v"(r) : "v"(lo), "v"(hi));
  return r;
}

DEVI float exp2v(float x) {
  float r;
  asm("v_exp_f32 %0, %1" : "=v"(r) : "v"(x));
  return r;
}

DEVI void store_bf4(unsigned short* dst, float4 v) {
  uint2 p;
  p.x = cvt_pk_bf16(v.x, v.y);
  p.y = cvt_pk_bf16(v.z, v.w);
  *reinterpret_cast<uint2*>(dst) = p;
}

// ---------------- kernel 1: QKV projection (bf16 MFMA GEMM + scatter) -------
// Q is pre-scaled by temperature[h] * log2(e) so attention can use exp2 directly.
__global__ __launch_bounds__(256) void qkv_kernel(
    const float* __restrict__ X, const float* __restrict__ S,
    const float* __restrict__ Wqkv, const float* __restrict__ temp,
    unsigned short* __restrict__ Qb, unsigned short* __restrict__ Kb,
    unsigned short* __restrict__ Vt)
{
  __shared__ __align__(16) unsigned short Al[64 * 200];  // 64 rows x 192, stride 200
  __shared__ __align__(16) unsigned short Wl[64 * 200];
  const int tid = threadIdx.x;
  const int m0 = blockIdx.x * 64, o0 = blockIdx.y * 64;
  {
    const int r = tid >> 2, c0 = (tid & 3) * 48;
    const int g = m0 + r;
    if (g < M_) {
      const int b = g / NT_, n = g % NT_;
      const float* src = (n < N_) ? (X + ((size_t)b * N_ + n) * C_)
                                  : (S + ((size_t)b * KS_ + (n - N_)) * C_);
      #pragma unroll
      for (int j = 0; j < 48; j += 4)
        store_bf4(&Al[r * 200 + c0 + j], *reinterpret_cast<const float4*>(src + c0 + j));
    }
    const float* wsrc = Wqkv + (size_t)(o0 + r) * C_;
    #pragma unroll
    for (int j = 0; j < 48; j += 4)
      store_bf4(&Wl[r * 200 + c0 + j], *reinterpret_cast<const float4*>(wsrc + c0 + j));
  }
  __syncthreads();
  const int w = tid >> 6, lane = tid & 63, lr = lane & 15, lg = lane >> 4;
  f32x4 acc[4] = {};
  #pragma unroll
  for (int kk = 0; kk < 6; ++kk) {
    s8v af = *reinterpret_cast<const s8v*>(&Al[(w * 16 + lr) * 200 + kk * 32 + lg * 8]);
    #pragma unroll
    for (int f = 0; f < 4; ++f) {
      s8v bf = *reinterpret_cast<const s8v*>(&Wl[(f * 16 + lr) * 200 + kk * 32 + lg * 8]);
      acc[f] = mfma16(af, bf, acc[f]);
    }
  }
  #pragma unroll
  for (int f = 0; f < 4; ++f) {
    #pragma unroll
    for (int r4 = 0; r4 < 4; ++r4) {
      const int grow = m0 + w * 16 + lg * 4 + r4;
      if (grow >= M_) continue;
      const int b = grow / NT_, n = grow % NT_;
      const int o = o0 + f * 16 + lr;
      const int which = o / C_, oc = o % C_;
      const int h = oc / D_, d = oc % D_;
      const int bh = b * H_ + h;
      if (which == 0) {
        const float qs = temp[h] * LOG2E_;
        Qb[((size_t)bh * NP_ + n) * DP_ + d] = f2bf(acc[f][r4] * qs);
      } else if (which == 1) {
        Kb[((size_t)bh * NP_ + n) * DP_ + d] = f2bf(acc[f][r4]);
      } else {
        Vt[((size_t)bh * DP_ + d) * NP_ + n] = f2bf(acc[f][r4]);  // V transposed
      }
    }
  }
}

// ---------------- kernel 2: flash attention -------------------------------
// 4 waves/block, 16 q-rows per wave. Swapped QK^T: sa = mfma(K, Q) so each
// lane owns a 16-kv slice of ONE q-row (q = lane&15) -> scalar m/l, cheap
// reduce, vector b64 P writes.
__global__ __launch_bounds__(256) void attn_kernel(
    const unsigned short* __restrict__ Qb, const unsigned short* __restrict__ Kb,
    const unsigned short* __restrict__ Vt,
    unsigned short* __restrict__ AO)
{
  __shared__ __align__(16) unsigned short Kl[64 * 40];      // K tile [64 kv][32 d]
  __shared__ __align__(16) unsigned short Vl[32 * 72];      // V^T tile [32 d][64 kv]
  __shared__ __align__(16) unsigned short Pl[4][16 * 72];   // per-wave P [16 q][64 kv]
  const int bh = blockIdx.y, h = bh & (H_ - 1), b = bh >> 3;
  const int tid = threadIdx.x, w = tid >> 6, lane = tid & 63, lr = lane & 15, lg = lane >> 4;
  const int q0 = blockIdx.x * 64 + w * 16;
  const unsigned short* Qp = Qb + (size_t)bh * NP_ * DP_;
  const unsigned short* Kp = Kb + (size_t)bh * NP_ * DP_;
  const unsigned short* Vp = Vt + (size_t)bh * DP_ * NP_;

  s8v qf;
  {
    int r = q0 + lr;
    if (r > NT_ - 1) r = NT_ - 1;               // clamp (stores skipped later)
    qf = *reinterpret_cast<const s8v*>(&Qp[(size_t)r * DP_ + lg * 8]);
  }
  f32x4 oacc[2] = {};
  float m = -1e30f, l = 0.f;
  unsigned short* Pw = Pl[w];

  for (int t = 0; t < NP_ / 64; ++t) {
    {
      const int r = tid >> 2, c0 = (tid & 3) * 8;
      *reinterpret_cast<s8v*>(&Kl[r * 40 + c0]) =
          *reinterpret_cast<const s8v*>(&Kp[((size_t)(t * 64 + r)) * DP_ + c0]);
      const int dr = tid >> 3, cv = (tid & 7) * 8;
      *reinterpret_cast<s8v*>(&Vl[dr * 72 + cv]) =
          *reinterpret_cast<const s8v*>(&Vp[(size_t)dr * NP_ + t * 64 + cv]);
    }
    __syncthreads();

    // QK^T (swapped): sa[nf] holds S[kv = t*64+nf*16+lg*4+r4][q = lr]
    f32x4 sa[4];
    #pragma unroll
    for (int nf = 0; nf < 4; ++nf) {
      s8v kf = *reinterpret_cast<const s8v*>(&Kl[(nf * 16 + lr) * 40 + lg * 8]);
      f32x4 z = {};
      sa[nf] = mfma16(kf, qf, z);
    }

    if (t == NP_ / 64 - 1) {                    // only the last tile is partial
      #pragma unroll
      for (int nf = 0; nf < 4; ++nf)
        #pragma unroll
        for (int r4 = 0; r4 < 4; ++r4)
          if (t * 64 + nf * 16 + lg * 4 + r4 >= NT_) sa[nf][r4] = -1e30f;
    }

    // online softmax, base-2 domain (log2e folded into Q)
    float mt = fmaxf(fmaxf(fmaxf(sa[0][0], sa[0][1]), fmaxf(sa[0][2], sa[0][3])),
                     fmaxf(fmaxf(sa[1][0], sa[1][1]), fmaxf(sa[1][2], sa[1][3])));
    mt = fmaxf(mt, fmaxf(fmaxf(fmaxf(sa[2][0], sa[2][1]), fmaxf(sa[2][2], sa[2][3])),
                         fmaxf(fmaxf(sa[3][0], sa[3][1]), fmaxf(sa[3][2], sa[3][3]))));
    mt = fmaxf(mt, __shfl_xor(mt, 16));
    mt = fmaxf(mt, __shfl_xor(mt, 32));
    const float mn = fmaxf(m, mt);
    const float corr = exp2v(m - mn);
    m = mn;
    float rs = 0.f;
    #pragma unroll
    for (int nf = 0; nf < 4; ++nf)
      #pragma unroll
      for (int r4 = 0; r4 < 4; ++r4) {
        const float p = exp2v(sa[nf][r4] - mn);
        sa[nf][r4] = p;
        rs += p;
      }
    rs += __shfl_xor(rs, 16);
    rs += __shfl_xor(rs, 32);
    l = l * corr + rs;

    // pack P to bf16, vector b64 writes: Pw[q=lr][kv]
    #pragma unroll
    for (int nf = 0; nf < 4; ++nf) {
      uint2 pu;
      pu.x = cvt_pk_bf16(sa[nf][0], sa[nf][1]);
      pu.y = cvt_pk_bf16(sa[nf][2], sa[nf][3]);
      *reinterpret_cast<uint2*>(&Pw[lr * 72 + nf * 16 + lg * 4]) = pu;
    }

    // rescale O (rows q = lg*4+r4) with corr transposed from q=lr lanes
    #pragma unroll
    for (int r4 = 0; r4 < 4; ++r4) {
      const float ct = __shfl(corr, lg * 4 + r4);
      oacc[0][r4] *= ct;
      oacc[1][r4] *= ct;
    }

    asm volatile("s_waitcnt lgkmcnt(0)" ::: "memory");
    __builtin_amdgcn_sched_barrier(0);

    #pragma unroll
    for (int ks = 0; ks < 2; ++ks) {
      s8v pa = *reinterpret_cast<const s8v*>(&Pw[lr * 72 + ks * 32 + lg * 8]);
      #pragma unroll
      for (int df = 0; df < 2; ++df) {
        s8v vb = *reinterpret_cast<const s8v*>(&Vl[(df * 16 + lr) * 72 + ks * 32 + lg * 8]);
        oacc[df] = mfma16(pa, vb, oacc[df]);
      }
    }
    __syncthreads();
  }

  const float linv = 1.f / l;                   // per q = lr
  #pragma unroll
  for (int r4 = 0; r4 < 4; ++r4) {
    const float lt = __shfl(linv, lg * 4 + r4);
    const int row = q0 + lg * 4 + r4;
    if (row >= NT_) continue;
    #pragma unroll
    for (int df = 0; df < 2; ++df) {
      const int d = df * 16 + lr;
      if (d < D_)
        AO[((size_t)b * NT_ + row) * C_ + h * D_ + d] = f2bf(oacc[df][r4] * lt);
    }
  }
}

// ---------------- kernel 3: output projection ------------------------------
__global__ __launch_bounds__(256) void outproj_kernel(
    const unsigned short* __restrict__ AO, const float* __restrict__ Wout,
    float* __restrict__ out)
{
  __shared__ __align__(16) unsigned short Al[64 * 200];
  __shared__ __align__(16) unsigned short Wl[64 * 200];
  const int tid = threadIdx.x;
  const int m0 = blockIdx.x * 64, o0 = blockIdx.y * 64;
  {
    const int r = tid >> 2, c0 = (tid & 3) * 48;
    int g = m0 + r; if (g > M_ - 1) g = M_ - 1;
    #pragma unroll
    for (int j = 0; j < 48; j += 8)
      *reinterpret_cast<s8v*>(&Al[r * 200 + c0 + j]) =
          *reinterpret_cast<const s8v*>(&AO[(size_t)g * C_ + c0 + j]);
    const float* wsrc = Wout + (size_t)(o0 + r) * C_;
    #pragma unroll
    for (int j = 0; j < 48; j += 4)
      store_bf4(&Wl[r * 200 + c0 + j], *reinterpret_cast<const float4*>(wsrc + c0 + j));
  }
  __syncthreads();
  const int w = tid >> 6, lane = tid & 63, lr = lane & 15, lg = lane >> 4;
  f32x4 acc[4] = {};
  #pragma unroll
  for (int kk = 0; kk < 6; ++kk) {
    s8v af = *reinterpret_cast<const s8v*>(&Al[(w * 16 + lr) * 200 + kk * 32 + lg * 8]);
    #pragma unroll
    for (int f = 0; f < 4; ++f) {
      s8v bf = *reinterpret_cast<const s8v*>(&Wl[(f * 16 + lr) * 200 + kk * 32 + lg * 8]);
      acc[f] = mfma16(af, bf, acc[f]);
    }
  }
  #pragma unroll
  for (int f = 0; f < 4; ++f)
    #pragma unroll
    for (int r4 = 0; r4 < 4; ++r4) {
      const int grow = m0 + w * 16 + lg * 4 + r4;
      if (grow >= M_) continue;
      const int b = grow / NT_, n = grow % NT_;
      if (n >= N_) continue;                       // drop strategy-token rows
      out[((size_t)b * N_ + n) * C_ + o0 + f * 16 + lr] = acc[f][r4];
    }
}

// ---------------- launch ---------------------------------------------------
extern "C" void kernel_launch(void* const* d_in, const int* in_sizes, int n_in,
                              void* d_out, int out_size, void* d_ws, size_t ws_size,
                              hipStream_t stream) {
  const float* X    = (const float*)d_in[0];
  const float* S    = (const float*)d_in[1];
  const float* Wqkv = (const float*)d_in[2];
  const float* Wout = (const float*)d_in[3];
  const float* temp = (const float*)d_in[4];
  float* out = (float*)d_out;

  unsigned short* Qb = (unsigned short*)d_ws;
  const size_t qkv_elems = (size_t)B_ * H_ * NP_ * DP_;   // 2,129,920 shorts each
  unsigned short* Kb = Qb + qkv_elems;
  unsigned short* Vt = Kb + qkv_elems;
  unsigned short* AO = Vt + qkv_elems;                    // [M_][C_] bf16
  // total ws: (3*2,129,920 + 8208*192)*2 B ~= 15.9 MB

  qkv_kernel<<<dim3((M_ + 63) / 64, TC_ / 64), 256, 0, stream>>>(X, S, Wqkv, temp, Qb, Kb, Vt);
  attn_kernel<<<dim3((NT_ + 63) / 64, B_ * H_), 256, 0, stream>>>(Qb, Kb, Vt, AO);
  outproj_kernel<<<dim3((M_ + 63) / 64, C_ / 64), 256, 0, stream>>>(AO, Wout, out);
}

// Round 3
// 199.817 us; speedup vs baseline: 1.7990x; 1.1220x over previous
//
#include <hip/hip_runtime.h>

typedef short s8v __attribute__((ext_vector_type(8)));
typedef float f32x4 __attribute__((ext_vector_type(4)));

#define DEVI static __device__ __forceinline__

namespace {
constexpr int B_  = 2;
constexpr int N_  = 4096;
constexpr int KS_ = 8;
constexpr int C_  = 192;
constexpr int H_  = 8;
constexpr int D_  = 24;
constexpr int NT_ = 4104;        // N_ + KS_
constexpr int TC_ = 576;         // 3*C_
constexpr int NP_ = 4160;        // kv rows padded to 65*64
constexpr int DP_ = 32;          // head dim padded for K=32 MFMA
constexpr int M_  = B_ * NT_;    // 8208 total rows
constexpr float LOG2E_ = 1.4426950408889634f;
}

DEVI unsigned short f2bf(float f) {
  union { float f; unsigned u; } x; x.f = f;
  unsigned r = x.u + 0x7FFFu + ((x.u >> 16) & 1u);   // RNE
  return (unsigned short)(r >> 16);
}

DEVI f32x4 mfma16(s8v a, s8v b, f32x4 c) {
  return __builtin_amdgcn_mfma_f32_16x16x32_bf16(a, b, c, 0, 0, 0);
}

DEVI unsigned cvt_pk_bf16(float lo, float hi) {
  unsigned r;
  asm("v_cvt_pk_bf16_f32 %0, %1, %2" : "=v"(r) : "v"(lo), "v"(hi));
  return r;
}

DEVI float exp2v(float x) {
  float r;
  asm("v_exp_f32 %0, %1" : "=v"(r) : "v"(x));
  return r;
}

DEVI void store_bf4(unsigned short* dst, float4 v) {
  uint2 p;
  p.x = cvt_pk_bf16(v.x, v.y);
  p.y = cvt_pk_bf16(v.z, v.w);
  *reinterpret_cast<uint2*>(dst) = p;
}

// ---------------- kernel 1: QKV projection (bf16 MFMA GEMM + scatter) -------
// Q is pre-scaled by temperature[h] * log2(e) so attention can use exp2 directly.
__global__ __launch_bounds__(256) void qkv_kernel(
    const float* __restrict__ X, const float* __restrict__ S,
    const float* __restrict__ Wqkv, const float* __restrict__ temp,
    unsigned short* __restrict__ Qb, unsigned short* __restrict__ Kb,
    unsigned short* __restrict__ Vt)
{
  __shared__ __align__(16) unsigned short Al[64 * 200];  // 64 rows x 192, stride 200
  __shared__ __align__(16) unsigned short Wl[64 * 200];
  const int tid = threadIdx.x;
  const int m0 = blockIdx.x * 64, o0 = blockIdx.y * 64;
  {
    const int r = tid >> 2, c0 = (tid & 3) * 48;
    const int g = m0 + r;
    if (g < M_) {
      const int b = g / NT_, n = g % NT_;
      const float* src = (n < N_) ? (X + ((size_t)b * N_ + n) * C_)
                                  : (S + ((size_t)b * KS_ + (n - N_)) * C_);
      #pragma unroll
      for (int j = 0; j < 48; j += 4)
        store_bf4(&Al[r * 200 + c0 + j], *reinterpret_cast<const float4*>(src + c0 + j));
    }
    const float* wsrc = Wqkv + (size_t)(o0 + r) * C_;
    #pragma unroll
    for (int j = 0; j < 48; j += 4)
      store_bf4(&Wl[r * 200 + c0 + j], *reinterpret_cast<const float4*>(wsrc + c0 + j));
  }
  __syncthreads();
  const int w = tid >> 6, lane = tid & 63, lr = lane & 15, lg = lane >> 4;
  f32x4 acc[4] = {};
  #pragma unroll
  for (int kk = 0; kk < 6; ++kk) {
    s8v af = *reinterpret_cast<const s8v*>(&Al[(w * 16 + lr) * 200 + kk * 32 + lg * 8]);
    #pragma unroll
    for (int f = 0; f < 4; ++f) {
      s8v bf = *reinterpret_cast<const s8v*>(&Wl[(f * 16 + lr) * 200 + kk * 32 + lg * 8]);
      acc[f] = mfma16(af, bf, acc[f]);
    }
  }
  #pragma unroll
  for (int f = 0; f < 4; ++f) {
    #pragma unroll
    for (int r4 = 0; r4 < 4; ++r4) {
      const int grow = m0 + w * 16 + lg * 4 + r4;
      if (grow >= M_) continue;
      const int b = grow / NT_, n = grow % NT_;
      const int o = o0 + f * 16 + lr;
      const int which = o / C_, oc = o % C_;
      const int h = oc / D_, d = oc % D_;
      const int bh = b * H_ + h;
      if (which == 0) {
        const float qs = temp[h] * LOG2E_;
        Qb[((size_t)bh * NP_ + n) * DP_ + d] = f2bf(acc[f][r4] * qs);
      } else if (which == 1) {
        Kb[((size_t)bh * NP_ + n) * DP_ + d] = f2bf(acc[f][r4]);
      } else {
        Vt[((size_t)bh * DP_ + d) * NP_ + n] = f2bf(acc[f][r4]);  // V transposed
      }
    }
  }
}

// ---------------- kernel 2: flash attention -------------------------------
// 4 waves/block, 16 q-rows per wave. Swapped QK^T (lane owns one q row),
// conflict-free XOR-swizzled LDS, single barrier/tile, reg-staged double
// buffer (T14), defer-max (T13).
__global__ __launch_bounds__(256) void attn_kernel(
    const unsigned short* __restrict__ Qb, const unsigned short* __restrict__ Kb,
    const unsigned short* __restrict__ Vt,
    unsigned short* __restrict__ AO)
{
  __shared__ __align__(16) unsigned short Kl[2][64 * 32];   // [kv][d], swz c^=(r>>1)&3
  __shared__ __align__(16) unsigned short Vl[2][32 * 64];   // [d][kv], swz c^=r&7
  __shared__ __align__(16) unsigned short Pl[4][16 * 64];   // per-wave [q][kv], swz c^=r&7
  const int bh = blockIdx.y, h = bh & (H_ - 1), b = bh >> 3;
  const int tid = threadIdx.x, w = tid >> 6, lane = tid & 63, lr = lane & 15, lg = lane >> 4;
  const int q0 = blockIdx.x * 64 + w * 16;
  const unsigned short* Qp = Qb + (size_t)bh * NP_ * DP_;
  const unsigned short* Kp = Kb + (size_t)bh * NP_ * DP_;
  const unsigned short* Vp = Vt + (size_t)bh * DP_ * NP_;

  // staging addressing (loop-invariant)
  const int ksr = tid >> 2, ksc = tid & 3;                  // K: 64 rows x 4 16B-blocks
  const int vsr = tid >> 3, vsc = tid & 7;                  // V: 32 rows x 8 16B-blocks
  const int kw_off = ksr * 32 + 8 * (ksc ^ ((ksr >> 1) & 3));
  const int vw_off = vsr * 64 + 8 * (vsc ^ (vsr & 7));
  const unsigned short* Kg = Kp + (size_t)ksr * DP_ + ksc * 8;
  const unsigned short* Vg = Vp + (size_t)vsr * NP_ + vsc * 8;

  s8v qf;
  {
    int r = q0 + lr;
    if (r > NT_ - 1) r = NT_ - 1;               // clamp (stores skipped later)
    qf = *reinterpret_cast<const s8v*>(&Qp[(size_t)r * DP_ + lg * 8]);
  }

  // read/write LDS offsets (shorts, loop-invariant, swizzle-consistent)
  int kr_off[4], pr_off[2], vr_off[2][2], pw_off[4];
  #pragma unroll
  for (int nf = 0; nf < 4; ++nf) {
    kr_off[nf] = (nf * 16 + lr) * 32 + 8 * (lg ^ ((lr >> 1) & 3));
    pw_off[nf] = lr * 64 + 8 * ((2 * nf + (lg >> 1)) ^ (lr & 7)) + 4 * (lg & 1);
  }
  #pragma unroll
  for (int ks = 0; ks < 2; ++ks) {
    pr_off[ks] = lr * 64 + 8 * ((4 * ks + lg) ^ (lr & 7));
    #pragma unroll
    for (int df = 0; df < 2; ++df)
      vr_off[ks][df] = (df * 16 + lr) * 64 + 8 * ((4 * ks + lg) ^ (lr & 7));
  }

  unsigned short* Pw = Pl[w];
  f32x4 oacc[2] = {};
  float m = -1e30f, l = 0.f;

  // prologue: stage tile 0 into buffer 0
  {
    s8v k0 = *reinterpret_cast<const s8v*>(Kg);
    s8v v0 = *reinterpret_cast<const s8v*>(Vg);
    *reinterpret_cast<s8v*>(&Kl[0][kw_off]) = k0;
    *reinterpret_cast<s8v*>(&Vl[0][vw_off]) = v0;
  }
  __syncthreads();

  constexpr int TILES = NP_ / 64;   // 65
  int cur = 0;
  for (int t = 0; t < TILES; ++t) {
    // issue next tile's global loads early (latency hides under compute)
    s8v kreg, vreg;
    const bool have_next = (t + 1 < TILES);
    if (have_next) {
      kreg = *reinterpret_cast<const s8v*>(Kg + (size_t)(t + 1) * 64 * DP_);
      vreg = *reinterpret_cast<const s8v*>(Vg + (t + 1) * 64);
    }
    const unsigned short* Kc = Kl[cur];
    const unsigned short* Vc = Vl[cur];

    // QK^T (swapped): sa[nf][r4] = S[kv = t*64+nf*16+lg*4+r4][q = lr]
    f32x4 sa[4];
    #pragma unroll
    for (int nf = 0; nf < 4; ++nf) {
      s8v kf = *reinterpret_cast<const s8v*>(&Kc[kr_off[nf]]);
      f32x4 z = {};
      sa[nf] = mfma16(kf, qf, z);
    }

    if (t == TILES - 1) {                       // only the last tile is partial
      #pragma unroll
      for (int nf = 0; nf < 4; ++nf)
        #pragma unroll
        for (int r4 = 0; r4 < 4; ++r4)
          if (t * 64 + nf * 16 + lg * 4 + r4 >= NT_) sa[nf][r4] = -1e30f;
    }

    // online softmax, base-2 domain; per-lane scalar state (q = lr)
    float mt = fmaxf(fmaxf(fmaxf(sa[0][0], sa[0][1]), fmaxf(sa[0][2], sa[0][3])),
                     fmaxf(fmaxf(sa[1][0], sa[1][1]), fmaxf(sa[1][2], sa[1][3])));
    mt = fmaxf(mt, fmaxf(fmaxf(fmaxf(sa[2][0], sa[2][1]), fmaxf(sa[2][2], sa[2][3])),
                         fmaxf(fmaxf(sa[3][0], sa[3][1]), fmaxf(sa[3][2], sa[3][3]))));
    mt = fmaxf(mt, __shfl_xor(mt, 16));
    mt = fmaxf(mt, __shfl_xor(mt, 32));
    if (!__all(mt <= m + 8.f)) {                // defer-max: rescale only on growth
      const float mn = fmaxf(m, mt);
      const float corr = exp2v(m - mn);
      m = mn;
      l *= corr;
      #pragma unroll
      for (int r4 = 0; r4 < 4; ++r4) {
        const float ct = __shfl(corr, lg * 4 + r4);
        oacc[0][r4] *= ct;
        oacc[1][r4] *= ct;
      }
    }
    float rs = 0.f;
    #pragma unroll
    for (int nf = 0; nf < 4; ++nf)
      #pragma unroll
      for (int r4 = 0; r4 < 4; ++r4) {
        const float p = exp2v(sa[nf][r4] - m);
        sa[nf][r4] = p;
        rs += p;
      }
    rs += __shfl_xor(rs, 16);
    rs += __shfl_xor(rs, 32);
    l += rs;

    // pack P to bf16, swizzled b64 writes (wave-local)
    #pragma unroll
    for (int nf = 0; nf < 4; ++nf) {
      uint2 pu;
      pu.x = cvt_pk_bf16(sa[nf][0], sa[nf][1]);
      pu.y = cvt_pk_bf16(sa[nf][2], sa[nf][3]);
      *reinterpret_cast<uint2*>(&Pw[pw_off[nf]]) = pu;
    }
    asm volatile("s_waitcnt lgkmcnt(0)" ::: "memory");
    __builtin_amdgcn_sched_barrier(0);

    // PV
    #pragma unroll
    for (int ks = 0; ks < 2; ++ks) {
      s8v pa = *reinterpret_cast<const s8v*>(&Pw[pr_off[ks]]);
      #pragma unroll
      for (int df = 0; df < 2; ++df) {
        s8v vb = *reinterpret_cast<const s8v*>(&Vc[vr_off[ks][df]]);
        oacc[df] = mfma16(pa, vb, oacc[df]);
      }
    }

    // write next tile into the other buffer, one barrier per tile
    if (have_next) {
      *reinterpret_cast<s8v*>(&Kl[cur ^ 1][kw_off]) = kreg;
      *reinterpret_cast<s8v*>(&Vl[cur ^ 1][vw_off]) = vreg;
    }
    __syncthreads();
    cur ^= 1;
  }

  const float linv = 1.f / l;                   // per q = lr
  #pragma unroll
  for (int r4 = 0; r4 < 4; ++r4) {
    const float lt = __shfl(linv, lg * 4 + r4);
    const int row = q0 + lg * 4 + r4;
    if (row >= NT_) continue;
    #pragma unroll
    for (int df = 0; df < 2; ++df) {
      const int d = df * 16 + lr;
      if (d < D_)
        AO[((size_t)b * NT_ + row) * C_ + h * D_ + d] = f2bf(oacc[df][r4] * lt);
    }
  }
}

// ---------------- kernel 3: output projection ------------------------------
__global__ __launch_bounds__(256) void outproj_kernel(
    const unsigned short* __restrict__ AO, const float* __restrict__ Wout,
    float* __restrict__ out)
{
  __shared__ __align__(16) unsigned short Al[64 * 200];
  __shared__ __align__(16) unsigned short Wl[64 * 200];
  const int tid = threadIdx.x;
  const int m0 = blockIdx.x * 64, o0 = blockIdx.y * 64;
  {
    const int r = tid >> 2, c0 = (tid & 3) * 48;
    int g = m0 + r; if (g > M_ - 1) g = M_ - 1;
    #pragma unroll
    for (int j = 0; j < 48; j += 8)
      *reinterpret_cast<s8v*>(&Al[r * 200 + c0 + j]) =
          *reinterpret_cast<const s8v*>(&AO[(size_t)g * C_ + c0 + j]);
    const float* wsrc = Wout + (size_t)(o0 + r) * C_;
    #pragma unroll
    for (int j = 0; j < 48; j += 4)
      store_bf4(&Wl[r * 200 + c0 + j], *reinterpret_cast<const float4*>(wsrc + c0 + j));
  }
  __syncthreads();
  const int w = tid >> 6, lane = tid & 63, lr = lane & 15, lg = lane >> 4;
  f32x4 acc[4] = {};
  #pragma unroll
  for (int kk = 0; kk < 6; ++kk) {
    s8v af = *reinterpret_cast<const s8v*>(&Al[(w * 16 + lr) * 200 + kk * 32 + lg * 8]);
    #pragma unroll
    for (int f = 0; f < 4; ++f) {
      s8v bf = *reinterpret_cast<const s8v*>(&Wl[(f * 16 + lr) * 200 + kk * 32 + lg * 8]);
      acc[f] = mfma16(af, bf, acc[f]);
    }
  }
  #pragma unroll
  for (int f = 0; f < 4; ++f)
    #pragma unroll
    for (int r4 = 0; r4 < 4; ++r4) {
      const int grow = m0 + w * 16 + lg * 4 + r4;
      if (grow >= M_) continue;
      const int b = grow / NT_, n = grow % NT_;
      if (n >= N_) continue;                       // drop strategy-token rows
      out[((size_t)b * N_ + n) * C_ + o0 + f * 16 + lr] = acc[f][r4];
    }
}

// ---------------- launch ---------------------------------------------------
extern "C" void kernel_launch(void* const* d_in, const int* in_sizes, int n_in,
                              void* d_out, int out_size, void* d_ws, size_t ws_size,
                              hipStream_t stream) {
  const float* X    = (const float*)d_in[0];
  const float* S    = (const float*)d_in[1];
  const float* Wqkv = (const float*)d_in[2];
  const float* Wout = (const float*)d_in[3];
  const float* temp = (const float*)d_in[4];
  float* out = (float*)d_out;

  unsigned short* Qb = (unsigned short*)d_ws;
  const size_t qkv_elems = (size_t)B_ * H_ * NP_ * DP_;   // 2,129,920 shorts each
  unsigned short* Kb = Qb + qkv_elems;
  unsigned short* Vt = Kb + qkv_elems;
  unsigned short* AO = Vt + qkv_elems;                    // [M_][C_] bf16
  // total ws: (3*2,129,920 + 8208*192)*2 B ~= 15.9 MB

  qkv_kernel<<<dim3((M_ + 63) / 64, TC_ / 64), 256, 0, stream>>>(X, S, Wqkv, temp, Qb, Kb, Vt);
  attn_kernel<<<dim3((NT_ + 63) / 64, B_ * H_), 256, 0, stream>>>(Qb, Kb, Vt, AO);
  outproj_kernel<<<dim3((M_ + 63) / 64, C_ / 64), 256, 0, stream>>>(AO, Wout, out);
}

// Round 4
// 196.859 us; speedup vs baseline: 1.8260x; 1.0150x over previous
//
#include <hip/hip_runtime.h>

typedef short s8v __attribute__((ext_vector_type(8)));
typedef float f32x4 __attribute__((ext_vector_type(4)));

#define DEVI static __device__ __forceinline__

namespace {
constexpr int B_  = 2;
constexpr int N_  = 4096;
constexpr int KS_ = 8;
constexpr int C_  = 192;
constexpr int H_  = 8;
constexpr int D_  = 24;
constexpr int NT_ = 4104;        // N_ + KS_
constexpr int NP_ = 4160;        // kv rows padded to 65*64
constexpr int DP_ = 32;          // head dim padded for K=32 MFMA
constexpr int M_  = B_ * NT_;    // 8208 total rows
constexpr float LOG2E_ = 1.4426950408889634f;
}

DEVI unsigned short f2bf(float f) {
  union { float f; unsigned u; } x; x.f = f;
  unsigned r = x.u + 0x7FFFu + ((x.u >> 16) & 1u);   // RNE
  return (unsigned short)(r >> 16);
}

DEVI f32x4 mfma16(s8v a, s8v b, f32x4 c) {
  return __builtin_amdgcn_mfma_f32_16x16x32_bf16(a, b, c, 0, 0, 0);
}

DEVI unsigned cvt_pk_bf16(float lo, float hi) {
  unsigned r;
  asm("v_cvt_pk_bf16_f32 %0, %1, %2" : "=v"(r) : "v"(lo), "v"(hi));
  return r;
}

DEVI float exp2v(float x) {
  float r;
  asm("v_exp_f32 %0, %1" : "=v"(r) : "v"(x));
  return r;
}

DEVI float max3f(float a, float b, float c) { return fmaxf(fmaxf(a, b), c); }

DEVI void store_bf4(unsigned short* dst, float4 v) {
  uint2 p;
  p.x = cvt_pk_bf16(v.x, v.y);
  p.y = cvt_pk_bf16(v.z, v.w);
  *reinterpret_cast<uint2*>(dst) = p;
}

// ---------------- kernel 1: QKV projection (bf16 MFMA GEMM) ----------------
// blockIdx.y 0-2: Q (pre-scaled by temp[h]*log2e), 3-5: K, 6-8: V.
// V is stored transposed [bh][d][n]; epilogue transposes through LDS so the
// global stores are coalesced 16B chunks along n.
__global__ __launch_bounds__(256) void qkv_kernel(
    const float* __restrict__ X, const float* __restrict__ S,
    const float* __restrict__ Wqkv, const float* __restrict__ temp,
    unsigned short* __restrict__ Qb, unsigned short* __restrict__ Kb,
    unsigned short* __restrict__ Vt)
{
  __shared__ __align__(16) unsigned short Al[64 * 200];  // 64 rows x 192, stride 200
  __shared__ __align__(16) unsigned short Wl[64 * 200];
  const int tid = threadIdx.x;
  const int m0 = blockIdx.x * 64, o0 = blockIdx.y * 64;
  const int which = blockIdx.y / 3;            // 0=Q 1=K 2=V (block-uniform)
  {
    const int r = tid >> 2, c0 = (tid & 3) * 48;
    const int g = m0 + r;
    if (g < M_) {
      const int b = g / NT_, n = g % NT_;
      const float* src = (n < N_) ? (X + ((size_t)b * N_ + n) * C_)
                                  : (S + ((size_t)b * KS_ + (n - N_)) * C_);
      #pragma unroll
      for (int j = 0; j < 48; j += 4)
        store_bf4(&Al[r * 200 + c0 + j], *reinterpret_cast<const float4*>(src + c0 + j));
    }
    const float* wsrc = Wqkv + (size_t)(o0 + r) * C_;
    #pragma unroll
    for (int j = 0; j < 48; j += 4)
      store_bf4(&Wl[r * 200 + c0 + j], *reinterpret_cast<const float4*>(wsrc + c0 + j));
  }
  __syncthreads();
  const int w = tid >> 6, lane = tid & 63, lr = lane & 15, lg = lane >> 4;
  f32x4 acc[4] = {};
  #pragma unroll
  for (int kk = 0; kk < 6; ++kk) {
    s8v af = *reinterpret_cast<const s8v*>(&Al[(w * 16 + lr) * 200 + kk * 32 + lg * 8]);
    #pragma unroll
    for (int f = 0; f < 4; ++f) {
      s8v bf = *reinterpret_cast<const s8v*>(&Wl[(f * 16 + lr) * 200 + kk * 32 + lg * 8]);
      acc[f] = mfma16(af, bf, acc[f]);
    }
  }
  const int lc0 = (blockIdx.y - which * 3) * 64;   // col within the 192-wide output

  if (which == 2) {
    // ---- V: transpose 64x64 acc tile through LDS, coalesced stores along n
    __syncthreads();                                // all waves done with Al
    unsigned short* Tt = Al;                        // reuse as [c=64][r=64], stride 72
    #pragma unroll
    for (int f = 0; f < 4; ++f)
      #pragma unroll
      for (int r4 = 0; r4 < 4; ++r4)
        Tt[(f * 16 + lr) * 72 + w * 16 + lg * 4 + r4] = f2bf(acc[f][r4]);
    __syncthreads();
    const int c = tid >> 2, r0 = (tid & 3) * 16;
    const int vc = lc0 + c;                         // 0..191
    const int h = vc / 24, d = vc - h * 24;
    const int g0 = m0 + r0;
    const bool fast = (g0 / NT_ == (g0 + 15) / NT_) && (g0 + 15 < M_);
    if (fast) {
      const int b = g0 / NT_, n0 = g0 - b * NT_;
      const size_t base = ((size_t)(b * H_ + h) * DP_ + d) * NP_ + n0;
      *reinterpret_cast<uint4*>(&Vt[base]) = *reinterpret_cast<const uint4*>(&Tt[c * 72 + r0]);
      *reinterpret_cast<uint4*>(&Vt[base + 8]) = *reinterpret_cast<const uint4*>(&Tt[c * 72 + r0 + 8]);
    } else {
      for (int j = 0; j < 16; ++j) {
        const int g = g0 + j;
        if (g >= M_) break;
        const int b = g / NT_, n = g - b * NT_;
        Vt[((size_t)(b * H_ + h) * DP_ + d) * NP_ + n] = Tt[c * 72 + r0 + j];
      }
    }
  } else {
    // ---- Q / K: near-coalesced scalar stores into [bh][n][32]
    #pragma unroll
    for (int f = 0; f < 4; ++f) {
      #pragma unroll
      for (int r4 = 0; r4 < 4; ++r4) {
        const int grow = m0 + w * 16 + lg * 4 + r4;
        if (grow >= M_) continue;
        const int b = grow / NT_, n = grow % NT_;
        const int oc = lc0 + f * 16 + lr;
        const int h = oc / 24, d = oc - h * 24;
        const size_t idx = ((size_t)(b * H_ + h) * NP_ + n) * DP_ + d;
        if (which == 0) Qb[idx] = f2bf(acc[f][r4] * (temp[h] * LOG2E_));
        else            Kb[idx] = f2bf(acc[f][r4]);
      }
    }
  }
}

// ---------------- kernel 2: flash attention -------------------------------
// 2 waves/block, 16 q-rows per wave (grid 129x16 -> 8 blocks/CU by LDS).
// Swapped QK^T, XOR-swizzled LDS, reg-staged double buffer, speculative exp
// with defer-max (rescale path is rare and off the critical chain).
__global__ __launch_bounds__(128) void attn_kernel(
    const unsigned short* __restrict__ Qb, const unsigned short* __restrict__ Kb,
    const unsigned short* __restrict__ Vt,
    unsigned short* __restrict__ AO)
{
  __shared__ __align__(16) unsigned short Kl[2][64 * 32];   // [kv][d], swz c^=(r>>1)&3
  __shared__ __align__(16) unsigned short Vl[2][32 * 64];   // [d][kv], swz c^=r&7
  __shared__ __align__(16) unsigned short Pl[2][16 * 64];   // per-wave [q][kv], swz c^=r&7
  const int bh = blockIdx.y, h = bh & (H_ - 1), b = bh >> 3;
  const int tid = threadIdx.x, w = tid >> 6, lane = tid & 63, lr = lane & 15, lg = lane >> 4;
  const int q0 = blockIdx.x * 32 + w * 16;
  const unsigned short* Qp = Qb + (size_t)bh * NP_ * DP_;
  const unsigned short* Kp = Kb + (size_t)bh * NP_ * DP_;
  const unsigned short* Vp = Vt + (size_t)bh * DP_ * NP_;

  // staging addressing: 128 threads, 2 chunks each for K (64x32) and V (32x64)
  const int kr1 = tid >> 2, kcol = tid & 3, kr2 = kr1 + 32;
  const int vr1 = tid >> 3, vcol = tid & 7, vr2 = vr1 + 16;
  const int kw1 = kr1 * 32 + 8 * (kcol ^ ((kr1 >> 1) & 3));
  const int kw2 = kr2 * 32 + 8 * (kcol ^ ((kr2 >> 1) & 3));
  const int vw1 = vr1 * 64 + 8 * (vcol ^ (vr1 & 7));
  const int vw2 = vr2 * 64 + 8 * (vcol ^ (vr2 & 7));
  const unsigned short* Kg1 = Kp + (size_t)kr1 * DP_ + kcol * 8;
  const unsigned short* Kg2 = Kp + (size_t)kr2 * DP_ + kcol * 8;
  const unsigned short* Vg1 = Vp + (size_t)vr1 * NP_ + vcol * 8;
  const unsigned short* Vg2 = Vp + (size_t)vr2 * NP_ + vcol * 8;

  s8v qf;
  {
    int r = q0 + lr;
    if (r > NT_ - 1) r = NT_ - 1;               // clamp (stores skipped later)
    qf = *reinterpret_cast<const s8v*>(&Qp[(size_t)r * DP_ + lg * 8]);
  }

  // fragment LDS offsets (swizzle-consistent, loop-invariant)
  int kr_off[4], pr_off[2], vr_off[2][2], pw_off[4];
  #pragma unroll
  for (int nf = 0; nf < 4; ++nf) {
    kr_off[nf] = (nf * 16 + lr) * 32 + 8 * (lg ^ ((lr >> 1) & 3));
    pw_off[nf] = lr * 64 + 8 * ((2 * nf + (lg >> 1)) ^ (lr & 7)) + 4 * (lg & 1);
  }
  #pragma unroll
  for (int ks = 0; ks < 2; ++ks) {
    pr_off[ks] = lr * 64 + 8 * ((4 * ks + lg) ^ (lr & 7));
    #pragma unroll
    for (int df = 0; df < 2; ++df)
      vr_off[ks][df] = (df * 16 + lr) * 64 + 8 * ((4 * ks + lg) ^ (lr & 7));
  }

  unsigned short* Pw = Pl[w];
  f32x4 oacc[2] = {};
  float m = 0.f, lp = 0.f;      // m=0 start: scale-invariant, f32/bf16 absorb 2^m

  // prologue: stage tile 0 into buffer 0
  *reinterpret_cast<s8v*>(&Kl[0][kw1]) = *reinterpret_cast<const s8v*>(Kg1);
  *reinterpret_cast<s8v*>(&Kl[0][kw2]) = *reinterpret_cast<const s8v*>(Kg2);
  *reinterpret_cast<s8v*>(&Vl[0][vw1]) = *reinterpret_cast<const s8v*>(Vg1);
  *reinterpret_cast<s8v*>(&Vl[0][vw2]) = *reinterpret_cast<const s8v*>(Vg2);
  __syncthreads();

  constexpr int TILES = NP_ / 64;   // 65
  int cur = 0;
  for (int t = 0; t < TILES; ++t) {
    // issue next tile's global loads early (latency hides under compute)
    s8v kreg1, kreg2, vreg1, vreg2;
    const bool have_next = (t + 1 < TILES);
    if (have_next) {
      const size_t ko = (size_t)(t + 1) * 64 * DP_;
      kreg1 = *reinterpret_cast<const s8v*>(Kg1 + ko);
      kreg2 = *reinterpret_cast<const s8v*>(Kg2 + ko);
      vreg1 = *reinterpret_cast<const s8v*>(Vg1 + (t + 1) * 64);
      vreg2 = *reinterpret_cast<const s8v*>(Vg2 + (t + 1) * 64);
    }
    const unsigned short* Kc = Kl[cur];
    const unsigned short* Vc = Vl[cur];

    // QK^T (swapped): sa[nf][r4] = S[kv = t*64+nf*16+lg*4+r4][q = lr]
    f32x4 sa[4];
    #pragma unroll
    for (int nf = 0; nf < 4; ++nf) {
      s8v kf = *reinterpret_cast<const s8v*>(&Kc[kr_off[nf]]);
      f32x4 z = {};
      sa[nf] = mfma16(kf, qf, z);
    }
    if (t == TILES - 1) {
      #pragma unroll
      for (int nf = 0; nf < 4; ++nf)
        #pragma unroll
        for (int r4 = 0; r4 < 4; ++r4)
          if (t * 64 + nf * 16 + lg * 4 + r4 >= NT_) sa[nf][r4] = -1e30f;
    }

    // tile max via max3 triples (off the exp critical path)
    const float t0 = max3f(sa[0][0], sa[0][1], sa[0][2]);
    const float t1 = max3f(sa[0][3], sa[1][0], sa[1][1]);
    const float t2 = max3f(sa[1][2], sa[1][3], sa[2][0]);
    const float t3 = max3f(sa[2][1], sa[2][2], sa[2][3]);
    const float t4 = max3f(sa[3][0], sa[3][1], sa[3][2]);
    float mt = max3f(max3f(t0, t1, t2), max3f(t3, t4, sa[3][3]), -1e30f);
    mt = fmaxf(mt, __shfl_xor(mt, 16));
    mt = fmaxf(mt, __shfl_xor(mt, 32));

    // speculative exp with the current running max
    float rsl = 0.f;
    #pragma unroll
    for (int nf = 0; nf < 4; ++nf)
      #pragma unroll
      for (int r4 = 0; r4 < 4; ++r4) {
        const float p = exp2v(sa[nf][r4] - m);
        sa[nf][r4] = p;
        rsl += p;
      }
    #pragma unroll
    for (int nf = 0; nf < 4; ++nf) {
      uint2 pu;
      pu.x = cvt_pk_bf16(sa[nf][0], sa[nf][1]);
      pu.y = cvt_pk_bf16(sa[nf][2], sa[nf][3]);
      *reinterpret_cast<uint2*>(&Pw[pw_off[nf]]) = pu;
    }

    if (!__all(mt <= m + 8.f)) {                // rare: max grew, fix everything up
      const float mn = fmaxf(m, mt);
      const float corr = exp2v(m - mn);
      m = mn;
      lp *= corr;
      rsl *= corr;
      #pragma unroll
      for (int nf = 0; nf < 4; ++nf) {
        #pragma unroll
        for (int r4 = 0; r4 < 4; ++r4) sa[nf][r4] *= corr;
        uint2 pu;
        pu.x = cvt_pk_bf16(sa[nf][0], sa[nf][1]);
        pu.y = cvt_pk_bf16(sa[nf][2], sa[nf][3]);
        *reinterpret_cast<uint2*>(&Pw[pw_off[nf]]) = pu;   // rewrite (same wave, ordered)
      }
      #pragma unroll
      for (int r4 = 0; r4 < 4; ++r4) {
        const float ct = __shfl(corr, lg * 4 + r4);
        oacc[0][r4] *= ct;
        oacc[1][r4] *= ct;
      }
    }
    lp += rsl;

    asm volatile("s_waitcnt lgkmcnt(0)" ::: "memory");
    __builtin_amdgcn_sched_barrier(0);

    // PV
    #pragma unroll
    for (int ks = 0; ks < 2; ++ks) {
      s8v pa = *reinterpret_cast<const s8v*>(&Pw[pr_off[ks]]);
      #pragma unroll
      for (int df = 0; df < 2; ++df) {
        s8v vb = *reinterpret_cast<const s8v*>(&Vc[vr_off[ks][df]]);
        oacc[df] = mfma16(pa, vb, oacc[df]);
      }
    }

    if (have_next) {
      *reinterpret_cast<s8v*>(&Kl[cur ^ 1][kw1]) = kreg1;
      *reinterpret_cast<s8v*>(&Kl[cur ^ 1][kw2]) = kreg2;
      *reinterpret_cast<s8v*>(&Vl[cur ^ 1][vw1]) = vreg1;
      *reinterpret_cast<s8v*>(&Vl[cur ^ 1][vw2]) = vreg2;
    }
    __syncthreads();
    cur ^= 1;
  }

  // finish l: cross-lane-group sum (deferred from the loop)
  float l = lp;
  l += __shfl_xor(l, 16);
  l += __shfl_xor(l, 32);
  const float linv = 1.f / l;                   // per q = lr
  #pragma unroll
  for (int r4 = 0; r4 < 4; ++r4) {
    const float lt = __shfl(linv, lg * 4 + r4);
    const int row = q0 + lg * 4 + r4;
    if (row >= NT_) continue;
    #pragma unroll
    for (int df = 0; df < 2; ++df) {
      const int d = df * 16 + lr;
      if (d < D_)
        AO[((size_t)b * NT_ + row) * C_ + h * D_ + d] = f2bf(oacc[df][r4] * lt);
    }
  }
}

// ---------------- kernel 3: output projection ------------------------------
__global__ __launch_bounds__(256) void outproj_kernel(
    const unsigned short* __restrict__ AO, const float* __restrict__ Wout,
    float* __restrict__ out)
{
  __shared__ __align__(16) unsigned short Al[64 * 200];
  __shared__ __align__(16) unsigned short Wl[64 * 200];
  const int tid = threadIdx.x;
  const int m0 = blockIdx.x * 64, o0 = blockIdx.y * 64;
  {
    const int r = tid >> 2, c0 = (tid & 3) * 48;
    int g = m0 + r; if (g > M_ - 1) g = M_ - 1;
    #pragma unroll
    for (int j = 0; j < 48; j += 8)
      *reinterpret_cast<s8v*>(&Al[r * 200 + c0 + j]) =
          *reinterpret_cast<const s8v*>(&AO[(size_t)g * C_ + c0 + j]);
    const float* wsrc = Wout + (size_t)(o0 + r) * C_;
    #pragma unroll
    for (int j = 0; j < 48; j += 4)
      store_bf4(&Wl[r * 200 + c0 + j], *reinterpret_cast<const float4*>(wsrc + c0 + j));
  }
  __syncthreads();
  const int w = tid >> 6, lane = tid & 63, lr = lane & 15, lg = lane >> 4;
  f32x4 acc[4] = {};
  #pragma unroll
  for (int kk = 0; kk < 6; ++kk) {
    s8v af = *reinterpret_cast<const s8v*>(&Al[(w * 16 + lr) * 200 + kk * 32 + lg * 8]);
    #pragma unroll
    for (int f = 0; f < 4; ++f) {
      s8v bf = *reinterpret_cast<const s8v*>(&Wl[(f * 16 + lr) * 200 + kk * 32 + lg * 8]);
      acc[f] = mfma16(af, bf, acc[f]);
    }
  }
  #pragma unroll
  for (int f = 0; f < 4; ++f)
    #pragma unroll
    for (int r4 = 0; r4 < 4; ++r4) {
      const int grow = m0 + w * 16 + lg * 4 + r4;
      if (grow >= M_) continue;
      const int b = grow / NT_, n = grow % NT_;
      if (n >= N_) continue;                       // drop strategy-token rows
      out[((size_t)b * N_ + n) * C_ + o0 + f * 16 + lr] = acc[f][r4];
    }
}

// ---------------- launch ---------------------------------------------------
extern "C" void kernel_launch(void* const* d_in, const int* in_sizes, int n_in,
                              void* d_out, int out_size, void* d_ws, size_t ws_size,
                              hipStream_t stream) {
  const float* X    = (const float*)d_in[0];
  const float* S    = (const float*)d_in[1];
  const float* Wqkv = (const float*)d_in[2];
  const float* Wout = (const float*)d_in[3];
  const float* temp = (const float*)d_in[4];
  float* out = (float*)d_out;

  unsigned short* Qb = (unsigned short*)d_ws;
  const size_t qkv_elems = (size_t)B_ * H_ * NP_ * DP_;   // 2,129,920 shorts each
  unsigned short* Kb = Qb + qkv_elems;
  unsigned short* Vt = Kb + qkv_elems;
  unsigned short* AO = Vt + qkv_elems;                    // [M_][C_] bf16
  // total ws: (3*2,129,920 + 8208*192)*2 B ~= 15.9 MB

  qkv_kernel<<<dim3((M_ + 63) / 64, 9), 256, 0, stream>>>(X, S, Wqkv, temp, Qb, Kb, Vt);
  attn_kernel<<<dim3((NT_ + 31) / 32, B_ * H_), 128, 0, stream>>>(Qb, Kb, Vt, AO);
  outproj_kernel<<<dim3((M_ + 63) / 64, C_ / 64), 256, 0, stream>>>(AO, Wout, out);
}

// Round 6
// 181.992 us; speedup vs baseline: 1.9752x; 1.0817x over previous
//
#include <hip/hip_runtime.h>

typedef _Float16 h8v __attribute__((ext_vector_type(8)));
typedef float f32x4 __attribute__((ext_vector_type(4)));

#define DEVI static __device__ __forceinline__

namespace {
constexpr int B_  = 2;
constexpr int N_  = 4096;
constexpr int KS_ = 8;
constexpr int C_  = 192;
constexpr int H_  = 8;
constexpr int D_  = 24;
constexpr int NT_ = 4104;        // N_ + KS_
constexpr int NP_ = 4160;        // kv rows padded to 65*64
constexpr int DP_ = 32;          // head dim padded for K=32 MFMA
constexpr int M_  = B_ * NT_;    // 8208 total rows
constexpr int NQP_   = 4224;     // q rows padded to 33*128 (attn block coverage)
constexpr int SPLIT_ = 2;        // KV-split factor
constexpr int TILES_ = NP_ / 64; // 65
constexpr float LOG2E_ = 1.4426950408889634f;
}

// f32 -> f16 scalar (RNE via v_cvt_f16_f32)
DEVI unsigned short f2h(float f) {
  union { _Float16 h; unsigned short u; } x;
  x.h = (_Float16)f;
  return x.u;
}

// f32 pair -> packed f16x2 (v_cvt_pkrtz_f16_f32, 1 op / 2 values)
DEVI unsigned pkh(float lo, float hi) {
  unsigned r;
  asm("v_cvt_pkrtz_f16_f32 %0, %1, %2" : "=v"(r) : "v"(lo), "v"(hi));
  return r;
}

DEVI f32x4 mfmah(h8v a, h8v b, f32x4 c) {
  return __builtin_amdgcn_mfma_f32_16x16x32_f16(a, b, c, 0, 0, 0);
}

DEVI float exp2v(float x) {
  float r;
  asm("v_exp_f32 %0, %1" : "=v"(r) : "v"(x));
  return r;
}

DEVI float max3f(float a, float b, float c) { return fmaxf(fmaxf(a, b), c); }

DEVI void store_h4(unsigned short* dst, float4 v) {
  uint2 p;
  p.x = pkh(v.x, v.y);
  p.y = pkh(v.z, v.w);
  *reinterpret_cast<uint2*>(dst) = p;
}

// async global->LDS, 16B per lane; dest must be wave-uniform base (+lane*16 HW)
DEVI void gl16(const unsigned short* g, unsigned short* l) {
  __builtin_amdgcn_global_load_lds(
      (const __attribute__((address_space(1))) unsigned int*)g,
      (__attribute__((address_space(3))) unsigned int*)l, 16, 0, 0);
}

// ---------------- kernel 1: QKV projection (f16 MFMA GEMM) -----------------
// blockIdx.y 0-2: Q (pre-scaled by temp[h]*log2e), 3-5: K, 6-8: V.
__global__ __launch_bounds__(256) void qkv_kernel(
    const float* __restrict__ X, const float* __restrict__ S,
    const float* __restrict__ Wqkv, const float* __restrict__ temp,
    unsigned short* __restrict__ Qb, unsigned short* __restrict__ Kb,
    unsigned short* __restrict__ Vt)
{
  __shared__ __align__(16) unsigned short Al[64 * 200];  // 64 rows x 192, stride 200
  __shared__ __align__(16) unsigned short Wl[64 * 200];
  const int tid = threadIdx.x;
  const int m0 = blockIdx.x * 64, o0 = blockIdx.y * 64;
  const int which = blockIdx.y / 3;            // 0=Q 1=K 2=V (block-uniform)
  {
    const int r = tid >> 2, c0 = (tid & 3) * 48;
    const int g = m0 + r;
    if (g < M_) {
      const int b = g / NT_, n = g % NT_;
      const float* src = (n < N_) ? (X + ((size_t)b * N_ + n) * C_)
                                  : (S + ((size_t)b * KS_ + (n - N_)) * C_);
      #pragma unroll
      for (int j = 0; j < 48; j += 4)
        store_h4(&Al[r * 200 + c0 + j], *reinterpret_cast<const float4*>(src + c0 + j));
    }
    const float* wsrc = Wqkv + (size_t)(o0 + r) * C_;
    #pragma unroll
    for (int j = 0; j < 48; j += 4)
      store_h4(&Wl[r * 200 + c0 + j], *reinterpret_cast<const float4*>(wsrc + c0 + j));
  }
  __syncthreads();
  const int w = tid >> 6, lane = tid & 63, lr = lane & 15, lg = lane >> 4;
  f32x4 acc[4] = {};
  #pragma unroll
  for (int kk = 0; kk < 6; ++kk) {
    h8v af = *reinterpret_cast<const h8v*>(&Al[(w * 16 + lr) * 200 + kk * 32 + lg * 8]);
    #pragma unroll
    for (int f = 0; f < 4; ++f) {
      h8v bf = *reinterpret_cast<const h8v*>(&Wl[(f * 16 + lr) * 200 + kk * 32 + lg * 8]);
      acc[f] = mfmah(af, bf, acc[f]);
    }
  }
  const int lc0 = (blockIdx.y - which * 3) * 64;   // col within the 192-wide output

  if (which == 2) {
    // ---- V: transpose 64x64 acc tile through LDS, coalesced stores along n
    __syncthreads();
    unsigned short* Tt = Al;                        // reuse as [c=64][r=64], stride 72
    #pragma unroll
    for (int f = 0; f < 4; ++f)
      #pragma unroll
      for (int r4 = 0; r4 < 4; ++r4)
        Tt[(f * 16 + lr) * 72 + w * 16 + lg * 4 + r4] = f2h(acc[f][r4]);
    __syncthreads();
    const int c = tid >> 2, r0 = (tid & 3) * 16;
    const int vc = lc0 + c;                         // 0..191
    const int h = vc / 24, d = vc - h * 24;
    const int g0 = m0 + r0;
    const bool fast = (g0 / NT_ == (g0 + 15) / NT_) && (g0 + 15 < M_);
    if (fast) {
      const int b = g0 / NT_, n0 = g0 - b * NT_;
      const size_t base = ((size_t)(b * H_ + h) * DP_ + d) * NP_ + n0;
      *reinterpret_cast<uint4*>(&Vt[base]) = *reinterpret_cast<const uint4*>(&Tt[c * 72 + r0]);
      *reinterpret_cast<uint4*>(&Vt[base + 8]) = *reinterpret_cast<const uint4*>(&Tt[c * 72 + r0 + 8]);
    } else {
      for (int j = 0; j < 16; ++j) {
        const int g = g0 + j;
        if (g >= M_) break;
        const int b = g / NT_, n = g - b * NT_;
        Vt[((size_t)(b * H_ + h) * DP_ + d) * NP_ + n] = Tt[c * 72 + r0 + j];
      }
    }
  } else {
    // ---- Q/K: repack through LDS, 2 coalesced b128 stores per thread
    __syncthreads();
    unsigned short* Tt = Al;                        // reuse as [n-local 64][oc 64], stride 72
    #pragma unroll
    for (int f = 0; f < 4; ++f) {
      #pragma unroll
      for (int r4 = 0; r4 < 4; ++r4) {
        const int rloc = w * 16 + lg * 4 + r4;
        const int oc = lc0 + f * 16 + lr;
        float v = acc[f][r4];
        if (which == 0) v *= temp[(oc * 171) >> 12] * LOG2E_;
        Tt[rloc * 72 + f * 16 + lr] = f2h(v);
      }
    }
    __syncthreads();
    unsigned short* QK = (which == 0) ? Qb : Kb;
    #pragma unroll
    for (int i = 0; i < 2; ++i) {
      const int e = tid + 256 * i;
      const int rr = e >> 3, cc = e & 7;
      const int g = m0 + rr;
      if (g < M_) {
        const int b = g / NT_, n = g - b * NT_;
        const int oc0 = lc0 + cc * 8;               // 8|24 and 8|64: never crosses a head
        const int h = (oc0 * 171) >> 12, d0 = oc0 - h * 24;
        *reinterpret_cast<uint4*>(&QK[((size_t)(b * H_ + h) * NP_ + n) * DP_ + d0]) =
            *reinterpret_cast<const uint4*>(&Tt[rr * 72 + cc * 8]);
      }
    }
  }
}

// ---------------- kernel 2: flash attention (KV-split partials) ------------
// 4 waves x 32 q-rows, KV-split over blockIdx.z. global_load_lds staging with
// inverse-swizzled global source, one vmcnt(0)+barrier per tile.
__global__ __launch_bounds__(256, 4) void attn_kernel(
    const unsigned short* __restrict__ Qb, const unsigned short* __restrict__ Kb,
    const unsigned short* __restrict__ Vt, float* __restrict__ Part)
{
  __shared__ __align__(16) unsigned short Kl[2][64 * 32];   // [kv][d], swz c^=(r>>1)&3
  __shared__ __align__(16) unsigned short Vl[2][32 * 64];   // [d][kv], swz c^=r&7
  __shared__ __align__(16) unsigned short Pl[4][32 * 64];   // per-wave [q][kv], pswz
  const int bh = blockIdx.y, s = blockIdx.z;
  const int tid = threadIdx.x, w = tid >> 6, lane = tid & 63, lr = lane & 15, lg = lane >> 4;
  const int q0w = blockIdx.x * 128 + w * 32;
  const int t0 = s * 33, t1 = (s == 0) ? 33 : TILES_;       // 33 / 32 tiles
  const unsigned short* Qp = Qb + (size_t)bh * NP_ * DP_;
  const unsigned short* Kp = Kb + (size_t)bh * NP_ * DP_;
  const unsigned short* Vp = Vt + (size_t)bh * DP_ * NP_;

  // staging: linear LDS chunks, inverse-swizzled global source (rule 21)
  const int kR = tid >> 2, kC = tid & 3;
  const int vR = tid >> 3, vC = tid & 7;
  const unsigned short* KgL = Kp + (size_t)kR * DP_ + (kC ^ ((kR >> 1) & 3)) * 8;
  const unsigned short* VgL = Vp + (size_t)vR * NP_ + (vC ^ (vR & 7)) * 8;
  unsigned short* KlD[2] = { &Kl[0][w * 512], &Kl[1][w * 512] };   // wave-uniform bases
  unsigned short* VlD[2] = { &Vl[0][w * 512], &Vl[1][w * 512] };

  h8v qf[2];
  #pragma unroll
  for (int mi = 0; mi < 2; ++mi) {
    int r = q0w + 16 * mi + lr;
    if (r > NT_ - 1) r = NT_ - 1;               // clamp (partials ignored by combine)
    qf[mi] = *reinterpret_cast<const h8v*>(&Qp[(size_t)r * DP_ + lg * 8]);
  }

  // fragment LDS offsets (swizzle-consistent, loop-invariant)
  const int pswz = (lr & 7) ^ (((lr >> 3) & 1) << 2);
  int kr_off[4], vr_off[2][2], pw_off[2][4], pr_off[2][2];
  #pragma unroll
  for (int nf = 0; nf < 4; ++nf)
    kr_off[nf] = (nf * 16 + lr) * 32 + 8 * (lg ^ ((lr >> 1) & 3));
  #pragma unroll
  for (int ks = 0; ks < 2; ++ks)
    #pragma unroll
    for (int df = 0; df < 2; ++df)
      vr_off[ks][df] = (df * 16 + lr) * 64 + 8 * ((4 * ks + lg) ^ (lr & 7));
  #pragma unroll
  for (int mi = 0; mi < 2; ++mi) {
    #pragma unroll
    for (int nf = 0; nf < 4; ++nf)
      pw_off[mi][nf] = (16 * mi + lr) * 64 + 8 * ((2 * nf + (lg >> 1)) ^ pswz) + 4 * (lg & 1);
    #pragma unroll
    for (int ks = 0; ks < 2; ++ks)
      pr_off[mi][ks] = (16 * mi + lr) * 64 + 8 * ((4 * ks + lg) ^ pswz);
  }

  unsigned short* Pw = Pl[w];
  f32x4 oacc[2][2] = {};
  float m[2] = { 0.f, 0.f }, lp[2] = { 0.f, 0.f };   // m=0 start: scale-invariant

  // prologue: stage first tile into buffer 0
  gl16(KgL + (size_t)t0 * 64 * DP_, KlD[0]);
  gl16(VgL + (size_t)t0 * 64, VlD[0]);
  asm volatile("s_waitcnt vmcnt(0)" ::: "memory");
  __syncthreads();

  int cur = 0;
  for (int t = t0; t < t1; ++t) {
    const bool more = (t + 1 < t1);
    if (more) {
      gl16(KgL + (size_t)(t + 1) * 64 * DP_, KlD[cur ^ 1]);
      gl16(VgL + (size_t)(t + 1) * 64, VlD[cur ^ 1]);
    }
    const unsigned short* Kc = Kl[cur];
    const unsigned short* Vc = Vl[cur];

    // QK^T (swapped): sa[mi][nf][r4] = S[kv = t*64+nf*16+lg*4+r4][q = q0w+16mi+lr]
    h8v kf[4];
    #pragma unroll
    for (int nf = 0; nf < 4; ++nf)
      kf[nf] = *reinterpret_cast<const h8v*>(&Kc[kr_off[nf]]);
    f32x4 sa[2][4];
    #pragma unroll
    for (int nf = 0; nf < 4; ++nf) {
      f32x4 z = {};
      sa[0][nf] = mfmah(kf[nf], qf[0], z);
      sa[1][nf] = mfmah(kf[nf], qf[1], z);
    }
    if (t == TILES_ - 1) {                      // only the global last tile is partial
      #pragma unroll
      for (int mi = 0; mi < 2; ++mi)
        #pragma unroll
        for (int nf = 0; nf < 4; ++nf)
          #pragma unroll
          for (int r4 = 0; r4 < 4; ++r4)
            if (t * 64 + nf * 16 + lg * 4 + r4 >= NT_) sa[mi][nf][r4] = -1e30f;
    }

    #pragma unroll
    for (int mi = 0; mi < 2; ++mi) {
      // tile max (off the exp critical path)
      const float u0 = max3f(sa[mi][0][0], sa[mi][0][1], sa[mi][0][2]);
      const float u1 = max3f(sa[mi][0][3], sa[mi][1][0], sa[mi][1][1]);
      const float u2 = max3f(sa[mi][1][2], sa[mi][1][3], sa[mi][2][0]);
      const float u3 = max3f(sa[mi][2][1], sa[mi][2][2], sa[mi][2][3]);
      const float u4 = max3f(sa[mi][3][0], sa[mi][3][1], sa[mi][3][2]);
      float mt = max3f(max3f(u0, u1, u2), max3f(u3, u4, sa[mi][3][3]), -1e30f);
      mt = fmaxf(mt, __shfl_xor(mt, 16));
      mt = fmaxf(mt, __shfl_xor(mt, 32));

      // speculative exp with current running max
      float rsl = 0.f;
      #pragma unroll
      for (int nf = 0; nf < 4; ++nf)
        #pragma unroll
        for (int r4 = 0; r4 < 4; ++r4) {
          const float p = exp2v(sa[mi][nf][r4] - m[mi]);
          sa[mi][nf][r4] = p;
          rsl += p;
        }
      #pragma unroll
      for (int nf = 0; nf < 4; ++nf) {
        uint2 pu;
        pu.x = pkh(sa[mi][nf][0], sa[mi][nf][1]);
        pu.y = pkh(sa[mi][nf][2], sa[mi][nf][3]);
        *reinterpret_cast<uint2*>(&Pw[pw_off[mi][nf]]) = pu;
      }
      if (!__all(mt <= m[mi] + 8.f)) {          // rare: max grew, fix up
        const float mn = fmaxf(m[mi], mt);
        const float corr = exp2v(m[mi] - mn);
        m[mi] = mn;
        lp[mi] *= corr;
        rsl *= corr;
        #pragma unroll
        for (int nf = 0; nf < 4; ++nf) {
          #pragma unroll
          for (int r4 = 0; r4 < 4; ++r4) sa[mi][nf][r4] *= corr;
          uint2 pu;
          pu.x = pkh(sa[mi][nf][0], sa[mi][nf][1]);
          pu.y = pkh(sa[mi][nf][2], sa[mi][nf][3]);
          *reinterpret_cast<uint2*>(&Pw[pw_off[mi][nf]]) = pu;
        }
        #pragma unroll
        for (int r4 = 0; r4 < 4; ++r4) {
          const float ct = __shfl(corr, lg * 4 + r4);
          oacc[mi][0][r4] *= ct;
          oacc[mi][1][r4] *= ct;
        }
      }
      lp[mi] += rsl;
    }

    asm volatile("s_waitcnt lgkmcnt(0)" ::: "memory");
    __builtin_amdgcn_sched_barrier(0);

    // PV
    h8v vb[2][2];
    #pragma unroll
    for (int ks = 0; ks < 2; ++ks)
      #pragma unroll
      for (int df = 0; df < 2; ++df)
        vb[ks][df] = *reinterpret_cast<const h8v*>(&Vc[vr_off[ks][df]]);
    #pragma unroll
    for (int mi = 0; mi < 2; ++mi)
      #pragma unroll
      for (int ks = 0; ks < 2; ++ks) {
        h8v pa = *reinterpret_cast<const h8v*>(&Pw[pr_off[mi][ks]]);
        #pragma unroll
        for (int df = 0; df < 2; ++df)
          oacc[mi][df] = mfmah(pa, vb[ks][df], oacc[mi][df]);
      }

    if (more) {
      asm volatile("s_waitcnt vmcnt(0)" ::: "memory");
      __syncthreads();
      cur ^= 1;
    }
  }

  // epilogue: write fp32 partials (O unnormalized, m, l)
  float* base = Part + ((size_t)bh * NQP_ * SPLIT_ + s) * 32;
  #pragma unroll
  for (int mi = 0; mi < 2; ++mi) {
    float l = lp[mi];
    l += __shfl_xor(l, 16);
    l += __shfl_xor(l, 32);
    #pragma unroll
    for (int r4 = 0; r4 < 4; ++r4) {
      const int q = q0w + 16 * mi + lg * 4 + r4;
      float* row = base + (size_t)q * (SPLIT_ * 32);
      #pragma unroll
      for (int df = 0; df < 2; ++df) {
        const int d = df * 16 + lr;
        if (d < D_) row[d] = oacc[mi][df][r4];
      }
    }
    if (lg == 0) {
      const int q = q0w + 16 * mi + lr;
      float* row = base + (size_t)q * (SPLIT_ * 32);
      row[24] = m[mi];
      row[25] = l;
    }
  }
}

// ---------------- kernel 2b: split combine ---------------------------------
__global__ __launch_bounds__(256) void combine_kernel(
    const float* __restrict__ Part, unsigned short* __restrict__ AO)
{
  const int n = blockIdx.x * 256 + threadIdx.x;
  const int bh = blockIdx.y;
  if (n >= NT_) return;
  const float* p0 = Part + ((size_t)bh * NQP_ + n) * (SPLIT_ * 32);
  const float* p1 = p0 + 32;
  const float m0v = p0[24], l0 = p0[25], m1v = p1[24], l1 = p1[25];
  const float mx = fmaxf(m0v, m1v);
  float a0 = exp2v(m0v - mx), a1 = exp2v(m1v - mx);
  const float inv = 1.f / (a0 * l0 + a1 * l1);
  a0 *= inv; a1 *= inv;
  const int b = bh >> 3, h = bh & 7;
  unsigned short* dst = AO + ((size_t)b * NT_ + n) * C_ + h * D_;
  #pragma unroll
  for (int c = 0; c < 3; ++c) {
    const float4 xa = *reinterpret_cast<const float4*>(p0 + c * 8);
    const float4 xb = *reinterpret_cast<const float4*>(p0 + c * 8 + 4);
    const float4 ya = *reinterpret_cast<const float4*>(p1 + c * 8);
    const float4 yb = *reinterpret_cast<const float4*>(p1 + c * 8 + 4);
    float4 ra, rb;
    ra.x = a0 * xa.x + a1 * ya.x;  ra.y = a0 * xa.y + a1 * ya.y;
    ra.z = a0 * xa.z + a1 * ya.z;  ra.w = a0 * xa.w + a1 * ya.w;
    rb.x = a0 * xb.x + a1 * yb.x;  rb.y = a0 * xb.y + a1 * yb.y;
    rb.z = a0 * xb.z + a1 * yb.z;  rb.w = a0 * xb.w + a1 * yb.w;
    store_h4(dst + c * 8, ra);
    store_h4(dst + c * 8 + 4, rb);
  }
}

// ---------------- kernel 3: output projection ------------------------------
__global__ __launch_bounds__(256) void outproj_kernel(
    const unsigned short* __restrict__ AO, const float* __restrict__ Wout,
    float* __restrict__ out)
{
  __shared__ __align__(16) unsigned short Al[64 * 200];
  __shared__ __align__(16) unsigned short Wl[64 * 200];
  const int tid = threadIdx.x;
  const int m0 = blockIdx.x * 64, o0 = blockIdx.y * 64;
  {
    const int r = tid >> 2, c0 = (tid & 3) * 48;
    int g = m0 + r; if (g > M_ - 1) g = M_ - 1;
    #pragma unroll
    for (int j = 0; j < 48; j += 8)
      *reinterpret_cast<uint4*>(&Al[r * 200 + c0 + j]) =
          *reinterpret_cast<const uint4*>(&AO[(size_t)g * C_ + c0 + j]);
    const float* wsrc = Wout + (size_t)(o0 + r) * C_;
    #pragma unroll
    for (int j = 0; j < 48; j += 4)
      store_h4(&Wl[r * 200 + c0 + j], *reinterpret_cast<const float4*>(wsrc + c0 + j));
  }
  __syncthreads();
  const int w = tid >> 6, lane = tid & 63, lr = lane & 15, lg = lane >> 4;
  f32x4 acc[4] = {};
  #pragma unroll
  for (int kk = 0; kk < 6; ++kk) {
    h8v af = *reinterpret_cast<const h8v*>(&Al[(w * 16 + lr) * 200 + kk * 32 + lg * 8]);
    #pragma unroll
    for (int f = 0; f < 4; ++f) {
      h8v bf = *reinterpret_cast<const h8v*>(&Wl[(f * 16 + lr) * 200 + kk * 32 + lg * 8]);
      acc[f] = mfmah(af, bf, acc[f]);
    }
  }
  #pragma unroll
  for (int f = 0; f < 4; ++f)
    #pragma unroll
    for (int r4 = 0; r4 < 4; ++r4) {
      const int grow = m0 + w * 16 + lg * 4 + r4;
      if (grow >= M_) continue;
      const int b = grow / NT_, n = grow % NT_;
      if (n >= N_) continue;                       // drop strategy-token rows
      out[((size_t)b * N_ + n) * C_ + o0 + f * 16 + lr] = acc[f][r4];
    }
}

// ---------------- launch ---------------------------------------------------
extern "C" void kernel_launch(void* const* d_in, const int* in_sizes, int n_in,
                              void* d_out, int out_size, void* d_ws, size_t ws_size,
                              hipStream_t stream) {
  const float* X    = (const float*)d_in[0];
  const float* S    = (const float*)d_in[1];
  const float* Wqkv = (const float*)d_in[2];
  const float* Wout = (const float*)d_in[3];
  const float* temp = (const float*)d_in[4];
  float* out = (float*)d_out;

  unsigned short* Qb = (unsigned short*)d_ws;
  const size_t qkv_elems = (size_t)B_ * H_ * NP_ * DP_;   // 2,129,920 shorts each
  unsigned short* Kb = Qb + qkv_elems;
  unsigned short* Vt = Kb + qkv_elems;
  unsigned short* AO = Vt + qkv_elems;                    // [M_][C_] f16
  float* Part = (float*)(AO + (size_t)M_ * C_);           // [bh][NQP_][SPLIT_][32] f32
  // ws: 15.9 MB (qkv+AO) + 17.3 MB (Part) ~= 33.2 MB

  qkv_kernel<<<dim3((M_ + 63) / 64, 9), 256, 0, stream>>>(X, S, Wqkv, temp, Qb, Kb, Vt);
  attn_kernel<<<dim3(NQP_ / 128, B_ * H_, SPLIT_), 256, 0, stream>>>(Qb, Kb, Vt, Part);
  combine_kernel<<<dim3((NT_ + 255) / 256, B_ * H_), 256, 0, stream>>>(Part, AO);
  outproj_kernel<<<dim3((M_ + 63) / 64, C_ / 64), 256, 0, stream>>>(AO, Wout, out);
}